// Round 6
// baseline (1271.641 us; speedup 1.0000x reference)
//
#include <hip/hip_runtime.h>

#define NN 100000
#define NE 1600000
#define NS 13          // source slices: slice = src >> 13 (8192 nodes/slice)
#define SLICE_SHIFT 13
#define NPW 25         // nodes per wave; 4000 waves x 25 = 100000 exactly
#define NQ (NS * NN)   // 1,300,000 bucket counters
#define GRID_SCAN0 5079   // ceil(NQ/256)
#define GRID_SCAN1 20     // ceil(5079/256)

// ===================== build: per-(slice,dst) histogram =====================
__global__ __launch_bounds__(256) void hist2_k(const int* __restrict__ ei,
                                               int* __restrict__ cnt) {
    int e = blockIdx.x * 256 + threadIdx.x;
    int src = ei[e];
    int dst = ei[NE + e];
    atomicAdd(&cnt[(src >> SLICE_SHIFT) * NN + dst], 1);
}

// generic 256-chunk inclusive scan
__global__ __launch_bounds__(256) void scanA_k(const int* __restrict__ in,
                                               int* __restrict__ scanned,
                                               int* __restrict__ bsums, int n) {
    __shared__ int tmp[256];
    int i = blockIdx.x * 256 + threadIdx.x;
    int v = (i < n) ? in[i] : 0;
    tmp[threadIdx.x] = v;
    __syncthreads();
#pragma unroll
    for (int off = 1; off < 256; off <<= 1) {
        int t = (threadIdx.x >= off) ? tmp[threadIdx.x - off] : 0;
        __syncthreads();
        tmp[threadIdx.x] += t;
        __syncthreads();
    }
    if (i < n) scanned[i] = tmp[threadIdx.x];
    if (threadIdx.x == 255) bsums[blockIdx.x] = tmp[255];
}

// single-wave inclusive scan (n <= 64)
__global__ __launch_bounds__(64) void scanC_k(int* __restrict__ b, int n) {
    int t = threadIdx.x;
    int v = (t < n) ? b[t] : 0;
#pragma unroll
    for (int off = 1; off < 64; off <<= 1) {
        int u = __shfl_up(v, off);
        if (t >= off) v += u;
    }
    if (t < n) b[t] = v;
}

// Q[i] = exclusive prefix (bucket start); cursor = copy; Q[NQ] = NE
__global__ __launch_bounds__(256) void combine_k(const int* __restrict__ S0,
                                                 const int* __restrict__ S1,
                                                 const int* __restrict__ B1,
                                                 const int* __restrict__ cnt,
                                                 int* __restrict__ Q,
                                                 int* __restrict__ cursor) {
    int i = blockIdx.x * 256 + threadIdx.x;
    if (i < NQ) {
        int c0 = i >> 8;
        int addb = 0;
        if (c0 > 0) {
            int j = c0 - 1;
            addb = S1[j] + ((j >> 8) ? B1[(j >> 8) - 1] : 0);
        }
        int excl = S0[i] - cnt[i] + addb;
        Q[i] = excl;
        cursor[i] = excl;
    }
    if (i == NQ) Q[i] = NE;
}

// scatter edges into slice-major order; pack (dst%NPW)<<20 | src
__global__ __launch_bounds__(256) void fill2_k(const int* __restrict__ ei,
                                               int* __restrict__ cursor,
                                               int* __restrict__ packed) {
    int e = blockIdx.x * 256 + threadIdx.x;
    int src = ei[e];
    int dst = ei[NE + e];
    int pos = atomicAdd(&cursor[(src >> SLICE_SHIFT) * NN + dst], 1);
    packed[pos] = ((dst % NPW) << 20) | src;
}

// ===================== layer 1: gather(x,32ch) + MLP1 -> h =====================
// 8 waves/block; wave owns 25 nodes; LDS acc; lanes: c=lane&31 channel, p=lane>>5 edge parity.
__global__ __launch_bounds__(512) void fused1s(const float* __restrict__ x,
                                               const int* __restrict__ Q,
                                               const int* __restrict__ packed,
                                               const float* __restrict__ W1,
                                               const float* __restrict__ b1,
                                               const float* __restrict__ W2,
                                               const float* __restrict__ b2,
                                               float* __restrict__ h) {
    __shared__ float acc[8 * NPW * 32];   // 25.6 KB
    for (int i = threadIdx.x; i < 8 * NPW * 32; i += 512) acc[i] = 0.f;
    __syncthreads();

    int lane = threadIdx.x & 63;
    int wv = threadIdx.x >> 6;
    int gw = blockIdx.x * 8 + wv;
    int base = gw * NPW;
    bool active = (base < NN);
    int c = lane & 31;
    int p = lane >> 5;
    float* A = acc + wv * NPW * 32;

    for (int s = 0; s < NS; ++s) {
        if (active) {
            int e0 = Q[s * NN + base];
            int e1 = Q[s * NN + base + NPW];
            int e = e0 + p;
            for (; e + 6 < e1; e += 8) {           // 4 edges per parity group
                int pk0 = packed[e], pk1 = packed[e + 2];
                int pk2 = packed[e + 4], pk3 = packed[e + 6];
                float v0 = x[(size_t)(pk0 & 0xFFFFF) * 32 + c];
                float v1 = x[(size_t)(pk1 & 0xFFFFF) * 32 + c];
                float v2 = x[(size_t)(pk2 & 0xFFFFF) * 32 + c];
                float v3 = x[(size_t)(pk3 & 0xFFFFF) * 32 + c];
                atomicAdd(&A[(pk0 >> 20) * 32 + c], v0);
                atomicAdd(&A[(pk1 >> 20) * 32 + c], v1);
                atomicAdd(&A[(pk2 >> 20) * 32 + c], v2);
                atomicAdd(&A[(pk3 >> 20) * 32 + c], v3);
            }
            for (; e < e1; e += 2) {
                int pk = packed[e];
                atomicAdd(&A[(pk >> 20) * 32 + c],
                          x[(size_t)(pk & 0xFFFFF) * 32 + c]);
            }
        }
        __syncthreads();   // keep block's waves slice-synchronous
    }

    if (active) {
        float aval[NPW], hid[NPW], o[NPW];
#pragma unroll
        for (int k = 0; k < NPW; ++k)
            aval[k] = A[k * 32 + c] + x[(size_t)(base + k) * 32 + c];

        float bb1 = b1[lane];
#pragma unroll
        for (int k = 0; k < NPW; ++k) hid[k] = bb1;
        for (int i = 0; i < 32; ++i) {
            float w = W1[i * 64 + lane];
#pragma unroll
            for (int k = 0; k < NPW; ++k)
                hid[k] = fmaf(__shfl(aval[k], i), w, hid[k]);
        }
#pragma unroll
        for (int k = 0; k < NPW; ++k) hid[k] = fmaxf(hid[k], 0.f);

        float bb2 = b2[lane];
#pragma unroll
        for (int k = 0; k < NPW; ++k) o[k] = bb2;
        for (int j = 0; j < 64; ++j) {
            float w = W2[j * 64 + lane];
#pragma unroll
            for (int k = 0; k < NPW; ++k)
                o[k] = fmaf(__shfl(hid[k], j), w, o[k]);
        }
#pragma unroll
        for (int k = 0; k < NPW; ++k)
            h[(size_t)(base + k) * 64 + lane] = fmaxf(o[k], 0.f);
    }
}

// ===================== layer 2: gather(h,64ch) + MLP2 -> out =====================
__global__ __launch_bounds__(512) void fused2s(const float* __restrict__ h,
                                               const int* __restrict__ Q,
                                               const int* __restrict__ packed,
                                               const float* __restrict__ W3,
                                               const float* __restrict__ b3,
                                               const float* __restrict__ W4,
                                               const float* __restrict__ b4,
                                               float* __restrict__ out) {
    __shared__ float acc[8 * NPW * 64];   // 51.2 KB
    for (int i = threadIdx.x; i < 8 * NPW * 64; i += 512) acc[i] = 0.f;
    __syncthreads();

    int lane = threadIdx.x & 63;
    int wv = threadIdx.x >> 6;
    int gw = blockIdx.x * 8 + wv;
    int base = gw * NPW;
    bool active = (base < NN);
    float* A = acc + wv * NPW * 64;

    for (int s = 0; s < NS; ++s) {
        if (active) {
            int e0 = Q[s * NN + base];
            int e1 = Q[s * NN + base + NPW];
            int e = e0;
            for (; e + 3 < e1; e += 4) {
                int pk0 = packed[e], pk1 = packed[e + 1];
                int pk2 = packed[e + 2], pk3 = packed[e + 3];
                float v0 = h[(size_t)(pk0 & 0xFFFFF) * 64 + lane];
                float v1 = h[(size_t)(pk1 & 0xFFFFF) * 64 + lane];
                float v2 = h[(size_t)(pk2 & 0xFFFFF) * 64 + lane];
                float v3 = h[(size_t)(pk3 & 0xFFFFF) * 64 + lane];
                atomicAdd(&A[(pk0 >> 20) * 64 + lane], v0);
                atomicAdd(&A[(pk1 >> 20) * 64 + lane], v1);
                atomicAdd(&A[(pk2 >> 20) * 64 + lane], v2);
                atomicAdd(&A[(pk3 >> 20) * 64 + lane], v3);
            }
            for (; e < e1; ++e) {
                int pk = packed[e];
                atomicAdd(&A[(pk >> 20) * 64 + lane],
                          h[(size_t)(pk & 0xFFFFF) * 64 + lane]);
            }
        }
        __syncthreads();
    }

    if (active) {
        float aval[NPW], hid[NPW], o[NPW];
#pragma unroll
        for (int k = 0; k < NPW; ++k)
            aval[k] = A[k * 64 + lane] + h[(size_t)(base + k) * 64 + lane];

        float bb3 = b3[lane];
#pragma unroll
        for (int k = 0; k < NPW; ++k) hid[k] = bb3;
        for (int i = 0; i < 64; ++i) {
            float w = W3[i * 64 + lane];
#pragma unroll
            for (int k = 0; k < NPW; ++k)
                hid[k] = fmaf(__shfl(aval[k], i), w, hid[k]);
        }
#pragma unroll
        for (int k = 0; k < NPW; ++k) hid[k] = fmaxf(hid[k], 0.f);

        float bb4 = b4[lane & 31];
#pragma unroll
        for (int k = 0; k < NPW; ++k) o[k] = bb4;
        for (int j = 0; j < 64; ++j) {
            float w = W4[j * 32 + (lane & 31)];
#pragma unroll
            for (int k = 0; k < NPW; ++k)
                o[k] = fmaf(__shfl(hid[k], j), w, o[k]);
        }
        if (lane < 32) {
#pragma unroll
            for (int k = 0; k < NPW; ++k)
                out[(size_t)(base + k) * 32 + lane] = o[k];
        }
    }
}

extern "C" void kernel_launch(void* const* d_in, const int* in_sizes, int n_in,
                              void* d_out, int out_size, void* d_ws, size_t ws_size,
                              hipStream_t stream) {
    const float* x  = (const float*)d_in[0];
    const int*   ei = (const int*)d_in[1];
    const float* W1 = (const float*)d_in[2];
    const float* b1 = (const float*)d_in[3];
    const float* W2 = (const float*)d_in[4];
    const float* b2 = (const float*)d_in[5];
    const float* W3 = (const float*)d_in[6];
    const float* b3 = (const float*)d_in[7];
    const float* W4 = (const float*)d_in[8];
    const float* b4 = (const float*)d_in[9];
    float* out = (float*)d_out;

    char* ws = (char*)d_ws;
    float* h      = (float*)ws;               ws += (size_t)NN * 64 * 4;      // 25.6 MB
    int*   packed = (int*)ws;                 ws += (size_t)NE * 4;           // 6.4 MB
    int*   Q      = (int*)ws;                 ws += (size_t)(NQ + 1) * 4;     // 5.2 MB

    // build-time arrays overlay the h region (dead before fused1s writes h)
    char* ov = (char*)h;
    int* cnt    = (int*)ov;                   ov += (size_t)NQ * 4;           // 5.2 MB
    int* S0     = (int*)ov;                   ov += (size_t)NQ * 4;           // 5.2 MB
    int* cursor = (int*)ov;                   ov += (size_t)NQ * 4;           // 5.2 MB
    int* B0     = (int*)ov;                   ov += (size_t)GRID_SCAN0 * 4;
    int* S1     = (int*)ov;                   ov += (size_t)GRID_SCAN0 * 4;
    int* B1     = (int*)ov;                   ov += (size_t)64 * 4;

    // ---- slice-major CSR build ----
    hipMemsetAsync(cnt, 0, (size_t)NQ * 4, stream);
    hist2_k<<<NE / 256, 256, 0, stream>>>(ei, cnt);
    scanA_k<<<GRID_SCAN0, 256, 0, stream>>>(cnt, S0, B0, NQ);
    scanA_k<<<GRID_SCAN1, 256, 0, stream>>>(B0, S1, B1, GRID_SCAN0);
    scanC_k<<<1, 64, 0, stream>>>(B1, GRID_SCAN1);
    combine_k<<<GRID_SCAN0, 256, 0, stream>>>(S0, S1, B1, cnt, Q, cursor);
    fill2_k<<<NE / 256, 256, 0, stream>>>(ei, cursor, packed);

    // ---- slice-synchronous fused layers (512 blocks x 8 waves, all co-resident) ----
    fused1s<<<512, 512, 0, stream>>>(x, Q, packed, W1, b1, W2, b2, h);
    fused2s<<<512, 512, 0, stream>>>(h, Q, packed, W3, b3, W4, b4, out);
}